// Round 14
// baseline (311.864 us; speedup 1.0000x reference)
//
#include <hip/hip_runtime.h>
#include <hip/hip_bf16.h>
#include <math.h>

// Problem constants (from reference setup_inputs)
constexpr int Bc  = 2;
constexpr int Sc  = 2048;
constexpr int Hc  = 512;
constexpr int NHc = 8;
constexpr int Tc  = Bc * Sc;      // 4096 tokens
constexpr int Ec  = 64;           // experts
constexpr int Fc  = 2048;         // ffn dim
constexpr int Cap = 256;          // capacity = 2 * T * 2 / E

typedef __attribute__((ext_vector_type(8))) short bf16x8;
typedef __attribute__((ext_vector_type(4))) float f32x4;

__device__ __forceinline__ unsigned short f2b(float f) {
    union { float f; unsigned u; } v; v.f = f;
    unsigned r = v.u + 0x7FFF + ((v.u >> 16) & 1);   // RTNE
    return (unsigned short)(r >> 16);
}

__device__ __forceinline__ float b2f(unsigned short u) {
    union { unsigned u; float f; } v; v.u = ((unsigned)u) << 16; return v.f;
}

__device__ __forceinline__ unsigned cvt_pk_bf16(float lo, float hi) {
    unsigned r;
    asm volatile("v_cvt_pk_bf16_f32 %0, %1, %2" : "=v"(r) : "v"(lo), "v"(hi));
    return r;
}

__device__ __forceinline__ float gelu_f(float x) {
    // tanh-approx gelu via exp2: gelu = x / (1 + 2^(-k*(x+0.044715 x^3)))
    float u = x + 0.044715f * x * x * x;
    float r = __builtin_amdgcn_exp2f(-2.302211692851f * u);
    return x * __builtin_amdgcn_rcpf(1.0f + r);
}

// ---------------- LN1: one wave per row, 4 rows/block ------------------------
__global__ __launch_bounds__(256) void ln_rows_kernel(const float* __restrict__ x,
                                                      const float* __restrict__ g,
                                                      const float* __restrict__ b,
                                                      unsigned short* __restrict__ o) {
    int w = threadIdx.x >> 6, l = threadIdx.x & 63;
    int t = blockIdx.x * 4 + w;
    const float4* row = (const float4*)(x + (size_t)t * Hc);
    float4 a = row[l], c = row[l + 64];
    float s  = a.x + a.y + a.z + a.w + c.x + c.y + c.z + c.w;
    float s2 = a.x * a.x + a.y * a.y + a.z * a.z + a.w * a.w
             + c.x * c.x + c.y * c.y + c.z * c.z + c.w * c.w;
    #pragma unroll
    for (int off = 32; off; off >>= 1) {
        s  += __shfl_xor(s,  off);
        s2 += __shfl_xor(s2, off);
    }
    float mean = s * (1.0f / Hc);
    float var  = s2 * (1.0f / Hc) - mean * mean;
    float r = rsqrtf(var + 1e-5f);
    float4 g0 = ((const float4*)g)[l], g1 = ((const float4*)g)[l + 64];
    float4 b0 = ((const float4*)b)[l], b1 = ((const float4*)b)[l + 64];
    ushort4 u0, u1;
    u0.x = f2b((a.x - mean) * r * g0.x + b0.x);
    u0.y = f2b((a.y - mean) * r * g0.y + b0.y);
    u0.z = f2b((a.z - mean) * r * g0.z + b0.z);
    u0.w = f2b((a.w - mean) * r * g0.w + b0.w);
    u1.x = f2b((c.x - mean) * r * g1.x + b1.x);
    u1.y = f2b((c.y - mean) * r * g1.y + b1.y);
    u1.z = f2b((c.z - mean) * r * g1.z + b1.z);
    u1.w = f2b((c.w - mean) * r * g1.w + b1.w);
    ((ushort4*)(o + (size_t)t * Hc))[l]      = u0;
    ((ushort4*)(o + (size_t)t * Hc))[l + 64] = u1;
}

// ---------------- MFMA bf16 GEMM, software-prefetched K-loop (R8-proven) -----
// C[M,N] = A[M,K](bf16) @ W[K,N](fp32 row-major), batched via blockIdx.z.
template <int BM, int EPI, int SWZ, typename TC>
__global__ __launch_bounds__(BM * 2) void gemm_mfma(const unsigned short* __restrict__ A,
                                                    const float* __restrict__ W,
                                                    TC* __restrict__ C,
                                                    const float* __restrict__ X,
                                                    int M, int N, int K,
                                                    long sA, long sW, long sC, long sX,
                                                    const float* __restrict__ Wb,
                                                    const float* __restrict__ Wc) {
    int bx = blockIdx.x, bz = blockIdx.z, by = blockIdx.y;
    if (SWZ) {
        int gx = gridDim.x;
        int nwg = gx * gridDim.z;
        int flat = bx + gx * bz;
        int wg = (flat & 7) * (nwg >> 3) + (flat >> 3);
        bx = wg % gx; bz = wg / gx;
    }
    A += (size_t)bz * sA;
    if (Wb) W = (bz == 0) ? W : ((bz == 1) ? Wb : Wc);
    else    W += (size_t)bz * sW;
    C += (size_t)bz * sC;
    if (X) X += (size_t)bz * sX;
    int m0 = by * BM, n0 = bx * 128;

    __shared__ unsigned short As[BM * 72];
    __shared__ unsigned short Bs[128 * 72];

    int tid = threadIdx.x;
    int wid = tid >> 6, lane = tid & 63;
    int wr = (wid >> 1) * 64, wc = (wid & 1) * 64;
    int lr = lane & 15, lg = lane >> 4;

    constexpr int WP = 512 / BM;
    bf16x8 areg[4];
    float4 wa[WP], wb[WP];

    auto load_tile = [&](int k0) {
        #pragma unroll
        for (int p = 0; p < 4; p++) {
            int e = p * 16 * BM + tid * 8;
            int row = e >> 6, col = e & 63;
            areg[p] = *(const bf16x8*)&A[(size_t)(m0 + row) * K + k0 + col];
        }
        #pragma unroll
        for (int p = 0; p < WP; p++) {
            int kp = (tid >> 5) + p * (BM / 16);
            int c  = (tid & 31) * 4;
            const float* w0 = &W[(size_t)(k0 + 2 * kp) * N + n0 + c];
            wa[p] = *(const float4*)w0;
            wb[p] = *(const float4*)(w0 + N);
        }
    };
    auto write_tile = [&]() {
        #pragma unroll
        for (int p = 0; p < 4; p++) {
            int e = p * 16 * BM + tid * 8;
            int row = e >> 6, col = e & 63;
            *(bf16x8*)&As[row * 72 + col] = areg[p];
        }
        #pragma unroll
        for (int p = 0; p < WP; p++) {
            int kp = (tid >> 5) + p * (BM / 16);
            int c  = (tid & 31) * 4;
            int qz = 8 * ((c >> 3) & 7);
            int kof = (2 * kp) ^ qz;
            *(ushort2*)&Bs[(c + 0) * 72 + kof] = (ushort2){f2b(wa[p].x), f2b(wb[p].x)};
            *(ushort2*)&Bs[(c + 1) * 72 + kof] = (ushort2){f2b(wa[p].y), f2b(wb[p].y)};
            *(ushort2*)&Bs[(c + 2) * 72 + kof] = (ushort2){f2b(wa[p].z), f2b(wb[p].z)};
            *(ushort2*)&Bs[(c + 3) * 72 + kof] = (ushort2){f2b(wa[p].w), f2b(wb[p].w)};
        }
    };

    f32x4 acc[4][4];
    #pragma unroll
    for (int i = 0; i < 4; i++)
        #pragma unroll
        for (int j = 0; j < 4; j++) acc[i][j] = (f32x4){0.f, 0.f, 0.f, 0.f};

    load_tile(0);
    int nsteps = K >> 6;
    for (int s = 0; s < nsteps; s++) {
        write_tile();                       // vmcnt wait here is 1 step old -> hidden
        if (s + 1 < nsteps) load_tile((s + 1) << 6);   // prefetch next step
        asm volatile("s_waitcnt lgkmcnt(0)" ::: "memory");
        __builtin_amdgcn_s_barrier();       // no vmcnt drain: loads stay in flight
        #pragma unroll
        for (int kk = 0; kk < 64; kk += 32) {
            bf16x8 af[4], bfr[4];
            #pragma unroll
            for (int i = 0; i < 4; i++) {
                af[i] = *(const bf16x8*)&As[(wr + i * 16 + lr) * 72 + kk + 8 * lg];
                int nrow = wc + i * 16 + lr;
                int qq = 8 * ((nrow >> 3) & 7);
                bfr[i] = *(const bf16x8*)&Bs[nrow * 72 + ((kk + 8 * lg) ^ qq)];
            }
            #pragma unroll
            for (int i = 0; i < 4; i++)
                #pragma unroll
                for (int j = 0; j < 4; j++)
                    acc[i][j] = __builtin_amdgcn_mfma_f32_16x16x32_bf16(af[i], bfr[j], acc[i][j], 0, 0, 0);
        }
        asm volatile("s_waitcnt lgkmcnt(0)" ::: "memory");
        __builtin_amdgcn_s_barrier();       // reads done before next overwrite
    }

    #pragma unroll
    for (int i = 0; i < 4; i++) {
        #pragma unroll
        for (int r = 0; r < 4; r++) {
            int m = m0 + wr + i * 16 + lg * 4 + r;
            #pragma unroll
            for (int j = 0; j < 4; j++) {
                int n = n0 + wc + j * 16 + lr;
                float vv = acc[i][j][r];
                if (EPI == 1) vv += X[(size_t)m * N + n];
                if (EPI == 2) { vv += X[n]; vv = gelu_f(vv); }
                if (EPI == 3) vv += X[n];
                if constexpr (sizeof(TC) == 2) C[(size_t)m * N + n] = (TC)f2b(vv);
                else                            C[(size_t)m * N + n] = vv;
            }
        }
    }
}

// ---------------- MFMA flash attention (R8 single-pass, proven) --------------
__global__ __launch_bounds__(256) void attn_mfma_kernel(const unsigned short* __restrict__ q,
                                                        const unsigned short* __restrict__ k,
                                                        const unsigned short* __restrict__ v,
                                                        unsigned short* __restrict__ o) {
    constexpr int LDK = 72;
    constexpr int NT  = Sc / 64;
    __shared__ unsigned short Ks[2][64 * LDK];
    __shared__ unsigned short Vt[2][64 * LDK];

    int flat = blockIdx.x;
    int wg = (flat & 7) * 64 + (flat >> 3);
    int qt = wg & 31;
    int hb = wg >> 5;
    int hh = hb & 7, b = hb >> 3;

    int q0 = qt * 64;
    int tid = threadIdx.x;
    int wid = tid >> 6, lane = tid & 63;
    int lr = lane & 15, lg = lane >> 4;

    const unsigned short* kbase = k + (size_t)(b * Sc) * Hc + hh * 64;
    const unsigned short* vbase = v + (size_t)(b * Sc) * Hc + hh * 64;

    bf16x8 qf[2];
    {
        const unsigned short* qrow = q + ((size_t)(b * Sc + q0 + wid * 16 + lr)) * Hc + hh * 64;
        qf[0] = *(const bf16x8*)&qrow[8 * lg];
        qf[1] = *(const bf16x8*)&qrow[32 + 8 * lg];
    }

    int krow = tid >> 3;
    int kcol = (tid & 7) * 8;
    int vk2  = (tid >> 4) * 2;
    int vd4  = (tid & 15) * 4;

    bf16x8 kr[2];
    ushort4 va[2], vb2[2];

    auto load_tile = [&](int kt) {
        #pragma unroll
        for (int p = 0; p < 2; p++) {
            kr[p] = *(const bf16x8*)&kbase[(size_t)(kt * 64 + p * 32 + krow) * Hc + kcol];
            const unsigned short* vp = &vbase[(size_t)(kt * 64 + p * 32 + vk2) * Hc + vd4];
            va[p]  = *(const ushort4*)vp;
            vb2[p] = *(const ushort4*)(vp + Hc);
        }
    };
    auto vswz = [](int d, int c) { return c ^ (8 * ((d >> 3) & 7)); };
    auto store_tile = [&](int bu) {
        #pragma unroll
        for (int p = 0; p < 2; p++) {
            *(bf16x8*)&Ks[bu][(p * 32 + krow) * LDK + kcol] = kr[p];
            int k2 = p * 32 + vk2;
            *(ushort2*)&Vt[bu][(vd4 + 0) * LDK + vswz(vd4 + 0, k2)] = (ushort2){va[p].x, vb2[p].x};
            *(ushort2*)&Vt[bu][(vd4 + 1) * LDK + vswz(vd4 + 1, k2)] = (ushort2){va[p].y, vb2[p].y};
            *(ushort2*)&Vt[bu][(vd4 + 2) * LDK + vswz(vd4 + 2, k2)] = (ushort2){va[p].z, vb2[p].z};
            *(ushort2*)&Vt[bu][(vd4 + 3) * LDK + vswz(vd4 + 3, k2)] = (ushort2){va[p].w, vb2[p].w};
        }
    };

    f32x4 Oacc[4];
    #pragma unroll
    for (int nb = 0; nb < 4; nb++) Oacc[nb] = (f32x4){0.f, 0.f, 0.f, 0.f};
    float mrun = -1e30f, lrun = 0.f;
    const float SCL2 = 0.125f * 1.4426950408889634f;

    load_tile(0);
    store_tile(0);
    __syncthreads();

    for (int kt = 0; kt < NT; kt++) {
        int cur = kt & 1;
        if (kt + 1 < NT) load_tile(kt + 1);

        f32x4 sacc[4];
        #pragma unroll
        for (int kb = 0; kb < 4; kb++) sacc[kb] = (f32x4){0.f, 0.f, 0.f, 0.f};
        __builtin_amdgcn_s_setprio(1);
        #pragma unroll
        for (int kb = 0; kb < 4; kb++) {
            #pragma unroll
            for (int s = 0; s < 2; s++) {
                bf16x8 kf = *(const bf16x8*)&Ks[cur][(kb * 16 + lr) * LDK + 32 * s + 8 * lg];
                sacc[kb] = __builtin_amdgcn_mfma_f32_16x16x32_bf16(kf, qf[s], sacc[kb], 0, 0, 0);
            }
        }
        __builtin_amdgcn_s_setprio(0);

        float z[4][4];
        float mt = -1e30f;
        #pragma unroll
        for (int kb = 0; kb < 4; kb++)
            #pragma unroll
            for (int r = 0; r < 4; r++) {
                z[kb][r] = sacc[kb][r] * SCL2;
                mt = fmaxf(mt, z[kb][r]);
            }
        mt = fmaxf(mt, __shfl_xor(mt, 16));
        mt = fmaxf(mt, __shfl_xor(mt, 32));

        bool defer = __all(mt - mrun <= 11.0f);
        float pv[4][4];
        float ps = 0.f;
        if (defer) {
            #pragma unroll
            for (int kb = 0; kb < 4; kb++)
                #pragma unroll
                for (int r = 0; r < 4; r++) {
                    pv[kb][r] = __builtin_amdgcn_exp2f(z[kb][r] - mrun);
                    ps += pv[kb][r];
                }
            ps += __shfl_xor(ps, 16);
            ps += __shfl_xor(ps, 32);
            lrun += ps;
        } else {
            float mnew = fmaxf(mrun, mt);
            float sc = __builtin_amdgcn_exp2f(mrun - mnew);
            #pragma unroll
            for (int kb = 0; kb < 4; kb++)
                #pragma unroll
                for (int r = 0; r < 4; r++) {
                    pv[kb][r] = __builtin_amdgcn_exp2f(z[kb][r] - mnew);
                    ps += pv[kb][r];
                }
            ps += __shfl_xor(ps, 16);
            ps += __shfl_xor(ps, 32);
            lrun = lrun * sc + ps;
            mrun = mnew;
            float scb[4];
            #pragma unroll
            for (int r = 0; r < 4; r++) scb[r] = __shfl(sc, lg * 4 + r);
            #pragma unroll
            for (int nb = 0; nb < 4; nb++)
                #pragma unroll
                for (int r = 0; r < 4; r++) Oacc[nb][r] *= scb[r];
        }

        unsigned d_[4][2];
        #pragma unroll
        for (int kb = 0; kb < 4; kb++) {
            d_[kb][0] = cvt_pk_bf16(pv[kb][0], pv[kb][1]);
            d_[kb][1] = cvt_pk_bf16(pv[kb][2], pv[kb][3]);
        }
        unsigned pfw[2][4];
        #pragma unroll
        for (int s = 0; s < 2; s++) {
            #pragma unroll
            for (int h = 0; h < 2; h++) {
                unsigned xx = d_[2 * s][h], yy = d_[2 * s + 1][h];
                asm volatile("v_permlane32_swap_b32 %0, %1" : "+v"(xx), "+v"(yy));
                asm volatile("v_permlane16_swap_b32 %0, %1" : "+v"(xx), "+v"(yy));
                pfw[s][h]     = xx;
                pfw[s][2 + h] = yy;
            }
        }
        bf16x8 pf0, pf1;
        *(unsigned*)&((short*)&pf0)[0] = pfw[0][0];
        *(unsigned*)&((short*)&pf0)[2] = pfw[0][1];
        *(unsigned*)&((short*)&pf0)[4] = pfw[0][2];
        *(unsigned*)&((short*)&pf0)[6] = pfw[0][3];
        *(unsigned*)&((short*)&pf1)[0] = pfw[1][0];
        *(unsigned*)&((short*)&pf1)[2] = pfw[1][1];
        *(unsigned*)&((short*)&pf1)[4] = pfw[1][2];
        *(unsigned*)&((short*)&pf1)[6] = pfw[1][3];

        __builtin_amdgcn_s_setprio(1);
        #pragma unroll
        for (int nb = 0; nb < 4; nb++) {
            f32x4 oa = Oacc[nb];
            int vrow = nb * 16 + lr;
            bf16x8 vf0 = *(const bf16x8*)&Vt[cur][vrow * LDK + vswz(vrow, 8 * lg)];
            bf16x8 vf1 = *(const bf16x8*)&Vt[cur][vrow * LDK + vswz(vrow, 32 + 8 * lg)];
            oa = __builtin_amdgcn_mfma_f32_16x16x32_bf16(pf0, vf0, oa, 0, 0, 0);
            oa = __builtin_amdgcn_mfma_f32_16x16x32_bf16(pf1, vf1, oa, 0, 0, 0);
            Oacc[nb] = oa;
        }
        __builtin_amdgcn_s_setprio(0);

        if (kt + 1 < NT) store_tile(cur ^ 1);
        __syncthreads();
    }

    float linv = 1.0f / lrun;
    unsigned short* ob = o + ((size_t)(b * Sc + q0 + wid * 16)) * Hc + hh * 64;
    #pragma unroll
    for (int r = 0; r < 4; r++) {
        float invB = __shfl(linv, lg * 4 + r);
        #pragma unroll
        for (int nb = 0; nb < 4; nb++) {
            ob[(size_t)(lg * 4 + r) * Hc + nb * 16 + lr] = f2b(Oacc[nb][r] * invB);
        }
    }
}

// ------- fused LN2 + router + top-2 + atomic-ticket dispatch (R10-verified) --
// One block per token. Exact fp32 gates. Atomic tickets produce the same
// (expert, pos) multiset as slot-order whenever no expert exceeds Cap;
// combine gathers via the same pos used for scatter -> identical output.
__global__ __launch_bounds__(256) void ln2rd_kernel(const float* __restrict__ xa,
                                                    const float* __restrict__ g,
                                                    const float* __restrict__ b,
                                                    const float* __restrict__ wr,
                                                    unsigned short* __restrict__ buf,
                                                    int* __restrict__ ef,
                                                    int* __restrict__ pos,
                                                    float* __restrict__ gf,
                                                    int* __restrict__ cnt) {
    int t = blockIdx.x;
    const float* row = xa + (size_t)t * Hc;
    int tid = threadIdx.x;
    int w = tid >> 6, l = tid & 63;
    float v0 = row[tid];
    float v1 = row[tid + 256];
    float s = v0 + v1, s2 = v0 * v0 + v1 * v1;
    for (int off = 32; off; off >>= 1) {
        s  += __shfl_down(s,  off);
        s2 += __shfl_down(s2, off);
    }
    __shared__ float ls[4], ls2[4];
    __shared__ float xn[512];
    __shared__ unsigned short xb[512];
    __shared__ float part[4][64];
    __shared__ int bc[4];
    if (l == 0) { ls[w] = s; ls2[w] = s2; }
    __syncthreads();
    if (tid == 0) {
        float a = 0.f, a2 = 0.f;
        for (int i = 0; i < 4; i++) { a += ls[i]; a2 += ls2[i]; }
        ls[0] = a; ls2[0] = a2;
    }
    __syncthreads();
    float mean = ls[0] * (1.0f / Hc);
    float var  = ls2[0] * (1.0f / Hc) - mean * mean;
    float r = rsqrtf(var + 1e-5f);
    float o0 = (v0 - mean) * r * g[tid]       + b[tid];
    float o1 = (v1 - mean) * r * g[tid + 256] + b[tid + 256];
    xn[tid] = o0; xn[tid + 256] = o1;
    xb[tid] = f2b(o0); xb[tid + 256] = f2b(o1);
    __syncthreads();

    // router: wave w covers h in [w*128, w*128+128); lane = expert
    float acc = 0.f;
    const float* wrow = wr + (size_t)(w * 128) * Ec + l;
    #pragma unroll 8
    for (int hh = 0; hh < 128; hh++)
        acc += xn[w * 128 + hh] * wrow[(size_t)hh * Ec];
    part[w][l] = acc;
    __syncthreads();
    if (w == 0) {
        float logit = part[0][l] + part[1][l] + part[2][l] + part[3][l];
        float mx = logit;
        for (int off = 32; off; off >>= 1) mx = fmaxf(mx, __shfl_xor(mx, off));
        float p = __expf(logit - mx);
        float sum = p;
        for (int off = 32; off; off >>= 1) sum += __shfl_xor(sum, off);
        p /= sum;
        float v1_ = p; int i1 = l;
        for (int off = 32; off; off >>= 1) {
            float ov = __shfl_xor(v1_, off);
            int   oi = __shfl_xor(i1, off);
            if (ov > v1_ || (ov == v1_ && oi < i1)) { v1_ = ov; i1 = oi; }
        }
        float v2_ = (l == i1) ? -INFINITY : p; int i2 = l;
        for (int off = 32; off; off >>= 1) {
            float ov = __shfl_xor(v2_, off);
            int   oi = __shfl_xor(i2, off);
            if (ov > v2_ || (ov == v2_ && oi < i2)) { v2_ = ov; i2 = oi; }
        }
        if (l == 0) {
            float inv = 1.0f / (v1_ + v2_);
            int p1 = atomicAdd(&cnt[i1], 1);
            int p2 = atomicAdd(&cnt[i2], 1);
            ef[t * 2]     = i1;  ef[t * 2 + 1]  = i2;
            pos[t * 2]    = p1;  pos[t * 2 + 1] = p2;
            gf[t * 2]     = v1_ * inv;
            gf[t * 2 + 1] = v2_ * inv;
            bc[0] = i1; bc[1] = i2; bc[2] = p1; bc[3] = p2;
        }
    }
    __syncthreads();
    int e1 = bc[0], e2 = bc[1], p1 = bc[2], p2 = bc[3];
    ushort2 u = *(ushort2*)&xb[tid * 2];
    if (p1 < Cap) ((ushort2*)(buf + ((size_t)e1 * Cap + p1) * Hc))[tid] = u;
    if (p2 < Cap) ((ushort2*)(buf + ((size_t)e2 * Cap + p2) * Hc))[tid] = u;
}

// ---------------- combine: out = xa + sum_k gate * y[ef,pos] (y bf16) --------
__global__ __launch_bounds__(128) void combine_kernel(const float* __restrict__ xa,
                                                      const unsigned short* __restrict__ y,
                                                      const int* __restrict__ ef,
                                                      const int* __restrict__ pos,
                                                      const float* __restrict__ gf,
                                                      float* __restrict__ out) {
    int t = blockIdx.x;
    int d = threadIdx.x;
    float4 acc = ((const float4*)(xa + (size_t)t * Hc))[d];
    #pragma unroll
    for (int kk = 0; kk < 2; kk++) {
        int s = t * 2 + kk;
        int p = pos[s];
        if (p < Cap) {
            float w = gf[s];
            ushort4 yv = ((const ushort4*)(y + ((size_t)ef[s] * Cap + p) * Hc))[d];
            acc.x += w * b2f(yv.x);
            acc.y += w * b2f(yv.y);
            acc.z += w * b2f(yv.z);
            acc.w += w * b2f(yv.w);
        }
    }
    ((float4*)(out + (size_t)t * Hc))[d] = acc;
}

// ---------------- launch -----------------------------------------------------
extern "C" void kernel_launch(void* const* d_in, const int* in_sizes, int n_in,
                              void* d_out, int out_size, void* d_ws, size_t ws_size,
                              hipStream_t stream) {
    const float* x     = (const float*)d_in[0];
    const float* ln1_g = (const float*)d_in[1];
    const float* ln1_b = (const float*)d_in[2];
    const float* wq    = (const float*)d_in[3];
    const float* wk    = (const float*)d_in[4];
    const float* wv    = (const float*)d_in[5];
    const float* wo    = (const float*)d_in[6];
    const float* ln2_g = (const float*)d_in[7];
    const float* ln2_b = (const float*)d_in[8];
    const float* wr    = (const float*)d_in[9];
    const float* w1    = (const float*)d_in[10];
    const float* b1    = (const float*)d_in[11];
    const float* w2    = (const float*)d_in[12];
    const float* b2    = (const float*)d_in[13];
    float* out = (float*)d_out;

    const size_t TH   = (size_t)Tc * Hc;        // 2,097,152
    const size_t ECH  = (size_t)Ec * Cap * Hc;  // 8,388,608
    const size_t ECF  = (size_t)Ec * Cap * Fc;  // 33,554,432
    const size_t HF   = (size_t)Hc * Fc;        // 1,048,576 (per-expert w size)

    // ---- workspace carve (bytes) ----
    char* wsb = (char*)d_ws;
    size_t off = 0;
    auto alloc = [&](size_t bytes) { size_t r = off; off = (off + bytes + 255) & ~(size_t)255; return r; };
    size_t x1b_off = alloc(TH * 2);       // bf16 x1
    size_t qkv_off = alloc(TH * 2 * 3);   // bf16 q|k|v contiguous
    size_t ab_off  = alloc(TH * 2);       // bf16 attention output
    size_t xa_off  = alloc(TH * 4);       // fp32 attn residual out
    size_t ef_off  = alloc((size_t)Tc * 2 * 4);
    size_t pos_off = alloc((size_t)Tc * 2 * 4);
    size_t gf_off  = alloc((size_t)Tc * 2 * 4);
    size_t cnt_off = alloc((size_t)Ec * 4);
    size_t buf_off = alloc(ECH * 2);      // bf16 expert inputs
    size_t h_off   = alloc(ECF * 2);      // bf16 h (all experts)
    size_t y_off   = alloc(ECH * 2);      // bf16 expert outputs
    if (ws_size < off) return;            // insufficient workspace

    unsigned short* x1b  = (unsigned short*)(wsb + x1b_off);
    unsigned short* qb   = (unsigned short*)(wsb + qkv_off);
    unsigned short* kb   = qb + TH;
    unsigned short* vb   = qb + 2 * TH;
    unsigned short* ab   = (unsigned short*)(wsb + ab_off);
    float* xa  = (float*)(wsb + xa_off);
    int*   ef  = (int*)(wsb + ef_off);
    int*   pos = (int*)(wsb + pos_off);
    float* gf  = (float*)(wsb + gf_off);
    int*   cnt = (int*)(wsb + cnt_off);
    unsigned short* bufb = (unsigned short*)(wsb + buf_off);
    unsigned short* h    = (unsigned short*)(wsb + h_off);
    unsigned short* y    = (unsigned short*)(wsb + y_off);

    dim3 blk(256);

    // 1. LN1 -> bf16 (wave per row)
    ln_rows_kernel<<<Tc / 4, blk, 0, stream>>>(x, ln1_g, ln1_b, x1b);

    // 2. fused QKV projections: one launch, z selects {wq,wk,wv} -> q|k|v
    gemm_mfma<128, 0, 0, unsigned short><<<dim3(Hc / 128, Tc / 128, 3), blk, 0, stream>>>(
        x1b, wq, qb, nullptr, Tc, Hc, Hc, 0, 0, (long)TH, 0, wk, wv);

    // 3. attention -> bf16 ab (single-pass, XCD-swizzled)
    attn_mfma_kernel<<<dim3(512), blk, 0, stream>>>(qb, kb, vb, ab);

    // 4. output projection + residual: xa = attn @ wo + x
    gemm_mfma<128, 1, 0, float><<<dim3(Hc / 128, Tc / 128, 1), blk, 0, stream>>>(
        ab, wo, xa, x, Tc, Hc, Hc, 0, 0, 0, 0, nullptr, nullptr);

    // 5. zero counters + fused LN2+router+top2+dispatch (replaces 3 launches)
    hipMemsetAsync(cnt, 0, Ec * sizeof(int), stream);
    ln2rd_kernel<<<Tc, blk, 0, stream>>>(xa, ln2_g, ln2_b, wr, bufb, ef, pos, gf, cnt);

    // 6. expert GEMM1: h = gelu(buf @ w1 + b1), BM=256 (w1 read exactly once)
    gemm_mfma<256, 2, 1, unsigned short><<<dim3(Fc / 128, Cap / 256, Ec), dim3(512), 0, stream>>>(
        bufb, w1, h, b1, Cap, Fc, Hc,
        (long)Cap * Hc, (long)HF, (long)Cap * Fc, (long)Fc, nullptr, nullptr);

    // 7. expert GEMM2: y = h @ w2 + b2 (bf16 out, XCD-swizzled)
    gemm_mfma<256, 3, 1, unsigned short><<<dim3(Hc / 128, Cap / 256, Ec), dim3(512), 0, stream>>>(
        h, w2, y, b2, Cap, Hc, Fc,
        (long)Cap * Fc, (long)HF, (long)Cap * Hc, (long)Hc, nullptr, nullptr);

    // 8. combine + final residual
    combine_kernel<<<Tc, dim3(128), 0, stream>>>(xa, y, ef, pos, gf, out);
}

// Round 15
// 291.732 us; speedup vs baseline: 1.0690x; 1.0690x over previous
//
#include <hip/hip_runtime.h>
#include <hip/hip_bf16.h>
#include <math.h>

// Problem constants (from reference setup_inputs)
constexpr int Bc  = 2;
constexpr int Sc  = 2048;
constexpr int Hc  = 512;
constexpr int NHc = 8;
constexpr int Tc  = Bc * Sc;      // 4096 tokens
constexpr int Ec  = 64;           // experts
constexpr int Fc  = 2048;         // ffn dim
constexpr int Cap = 256;          // capacity = 2 * T * 2 / E

typedef __attribute__((ext_vector_type(8))) short bf16x8;
typedef __attribute__((ext_vector_type(4))) float f32x4;

__device__ __forceinline__ unsigned short f2b(float f) {
    union { float f; unsigned u; } v; v.f = f;
    unsigned r = v.u + 0x7FFF + ((v.u >> 16) & 1);   // RTNE
    return (unsigned short)(r >> 16);
}

__device__ __forceinline__ float b2f(unsigned short u) {
    union { unsigned u; float f; } v; v.u = ((unsigned)u) << 16; return v.f;
}

__device__ __forceinline__ unsigned cvt_pk_bf16(float lo, float hi) {
    unsigned r;
    asm volatile("v_cvt_pk_bf16_f32 %0, %1, %2" : "=v"(r) : "v"(lo), "v"(hi));
    return r;
}

__device__ __forceinline__ float gelu_f(float x) {
    // tanh-approx gelu via exp2: gelu = x / (1 + 2^(-k*(x+0.044715 x^3)))
    float u = x + 0.044715f * x * x * x;
    float r = __builtin_amdgcn_exp2f(-2.302211692851f * u);
    return x * __builtin_amdgcn_rcpf(1.0f + r);
}

// ---------------- LN1: one wave per row, 4 rows/block ------------------------
__global__ __launch_bounds__(256) void ln_rows_kernel(const float* __restrict__ x,
                                                      const float* __restrict__ g,
                                                      const float* __restrict__ b,
                                                      unsigned short* __restrict__ o) {
    int w = threadIdx.x >> 6, l = threadIdx.x & 63;
    int t = blockIdx.x * 4 + w;
    const float4* row = (const float4*)(x + (size_t)t * Hc);
    float4 a = row[l], c = row[l + 64];
    float s  = a.x + a.y + a.z + a.w + c.x + c.y + c.z + c.w;
    float s2 = a.x * a.x + a.y * a.y + a.z * a.z + a.w * a.w
             + c.x * c.x + c.y * c.y + c.z * c.z + c.w * c.w;
    #pragma unroll
    for (int off = 32; off; off >>= 1) {
        s  += __shfl_xor(s,  off);
        s2 += __shfl_xor(s2, off);
    }
    float mean = s * (1.0f / Hc);
    float var  = s2 * (1.0f / Hc) - mean * mean;
    float r = rsqrtf(var + 1e-5f);
    float4 g0 = ((const float4*)g)[l], g1 = ((const float4*)g)[l + 64];
    float4 b0 = ((const float4*)b)[l], b1 = ((const float4*)b)[l + 64];
    ushort4 u0, u1;
    u0.x = f2b((a.x - mean) * r * g0.x + b0.x);
    u0.y = f2b((a.y - mean) * r * g0.y + b0.y);
    u0.z = f2b((a.z - mean) * r * g0.z + b0.z);
    u0.w = f2b((a.w - mean) * r * g0.w + b0.w);
    u1.x = f2b((c.x - mean) * r * g1.x + b1.x);
    u1.y = f2b((c.y - mean) * r * g1.y + b1.y);
    u1.z = f2b((c.z - mean) * r * g1.z + b1.z);
    u1.w = f2b((c.w - mean) * r * g1.w + b1.w);
    ((ushort4*)(o + (size_t)t * Hc))[l]      = u0;
    ((ushort4*)(o + (size_t)t * Hc))[l + 64] = u1;
}

// ---------------- MFMA bf16 GEMM, software-prefetched K-loop ----------------
// C[M,N] = A[M,K](bf16) @ W[K,N](fp32 row-major), batched via blockIdx.z.
// K-loop: write_tile(regs_s); load_tile(s+1); [lgkmcnt0; s_barrier]; compute;
// [s_barrier]. Global loads stay in flight across barriers (no vmcnt drain) ->
// HBM streams during compute; ds_write's vmcnt wait hidden by one full step.
template <int BM, int EPI, int SWZ, typename TC>
__global__ __launch_bounds__(BM * 2) void gemm_mfma(const unsigned short* __restrict__ A,
                                                    const float* __restrict__ W,
                                                    TC* __restrict__ C,
                                                    const float* __restrict__ X,
                                                    int M, int N, int K,
                                                    long sA, long sW, long sC, long sX,
                                                    const float* __restrict__ Wb,
                                                    const float* __restrict__ Wc) {
    int bx = blockIdx.x, bz = blockIdx.z, by = blockIdx.y;
    if (SWZ) {
        int gx = gridDim.x;
        int nwg = gx * gridDim.z;
        int flat = bx + gx * bz;
        int wg = (flat & 7) * (nwg >> 3) + (flat >> 3);
        bx = wg % gx; bz = wg / gx;
    }
    A += (size_t)bz * sA;
    if (Wb) W = (bz == 0) ? W : ((bz == 1) ? Wb : Wc);
    else    W += (size_t)bz * sW;
    C += (size_t)bz * sC;
    if (X) X += (size_t)bz * sX;
    int m0 = by * BM, n0 = bx * 128;

    __shared__ unsigned short As[BM * 72];
    __shared__ unsigned short Bs[128 * 72];

    int tid = threadIdx.x;
    int wid = tid >> 6, lane = tid & 63;
    int wr = (wid >> 1) * 64, wc = (wid & 1) * 64;
    int lr = lane & 15, lg = lane >> 4;

    constexpr int WP = 512 / BM;
    bf16x8 areg[4];
    float4 wa[WP], wb[WP];

    auto load_tile = [&](int k0) {
        #pragma unroll
        for (int p = 0; p < 4; p++) {
            int e = p * 16 * BM + tid * 8;
            int row = e >> 6, col = e & 63;
            areg[p] = *(const bf16x8*)&A[(size_t)(m0 + row) * K + k0 + col];
        }
        #pragma unroll
        for (int p = 0; p < WP; p++) {
            int kp = (tid >> 5) + p * (BM / 16);
            int c  = (tid & 31) * 4;
            const float* w0 = &W[(size_t)(k0 + 2 * kp) * N + n0 + c];
            wa[p] = *(const float4*)w0;
            wb[p] = *(const float4*)(w0 + N);
        }
    };
    auto write_tile = [&]() {
        #pragma unroll
        for (int p = 0; p < 4; p++) {
            int e = p * 16 * BM + tid * 8;
            int row = e >> 6, col = e & 63;
            *(bf16x8*)&As[row * 72 + col] = areg[p];
        }
        #pragma unroll
        for (int p = 0; p < WP; p++) {
            int kp = (tid >> 5) + p * (BM / 16);
            int c  = (tid & 31) * 4;
            int qz = 8 * ((c >> 3) & 7);
            int kof = (2 * kp) ^ qz;
            *(ushort2*)&Bs[(c + 0) * 72 + kof] = (ushort2){f2b(wa[p].x), f2b(wb[p].x)};
            *(ushort2*)&Bs[(c + 1) * 72 + kof] = (ushort2){f2b(wa[p].y), f2b(wb[p].y)};
            *(ushort2*)&Bs[(c + 2) * 72 + kof] = (ushort2){f2b(wa[p].z), f2b(wb[p].z)};
            *(ushort2*)&Bs[(c + 3) * 72 + kof] = (ushort2){f2b(wa[p].w), f2b(wb[p].w)};
        }
    };

    f32x4 acc[4][4];
    #pragma unroll
    for (int i = 0; i < 4; i++)
        #pragma unroll
        for (int j = 0; j < 4; j++) acc[i][j] = (f32x4){0.f, 0.f, 0.f, 0.f};

    load_tile(0);
    int nsteps = K >> 6;
    for (int s = 0; s < nsteps; s++) {
        write_tile();                       // vmcnt wait here is 1 step old -> hidden
        if (s + 1 < nsteps) load_tile((s + 1) << 6);   // prefetch next step
        asm volatile("s_waitcnt lgkmcnt(0)" ::: "memory");
        __builtin_amdgcn_s_barrier();       // no vmcnt drain: loads stay in flight
        #pragma unroll
        for (int kk = 0; kk < 64; kk += 32) {
            bf16x8 af[4], bfr[4];
            #pragma unroll
            for (int i = 0; i < 4; i++) {
                af[i] = *(const bf16x8*)&As[(wr + i * 16 + lr) * 72 + kk + 8 * lg];
                int nrow = wc + i * 16 + lr;
                int qq = 8 * ((nrow >> 3) & 7);
                bfr[i] = *(const bf16x8*)&Bs[nrow * 72 + ((kk + 8 * lg) ^ qq)];
            }
            #pragma unroll
            for (int i = 0; i < 4; i++)
                #pragma unroll
                for (int j = 0; j < 4; j++)
                    acc[i][j] = __builtin_amdgcn_mfma_f32_16x16x32_bf16(af[i], bfr[j], acc[i][j], 0, 0, 0);
        }
        asm volatile("s_waitcnt lgkmcnt(0)" ::: "memory");
        __builtin_amdgcn_s_barrier();       // reads done before next overwrite
    }

    #pragma unroll
    for (int i = 0; i < 4; i++) {
        #pragma unroll
        for (int r = 0; r < 4; r++) {
            int m = m0 + wr + i * 16 + lg * 4 + r;
            #pragma unroll
            for (int j = 0; j < 4; j++) {
                int n = n0 + wc + j * 16 + lr;
                float vv = acc[i][j][r];
                if (EPI == 1) vv += X[(size_t)m * N + n];
                if (EPI == 2) { vv += X[n]; vv = gelu_f(vv); }
                if (EPI == 3) vv += X[n];
                if constexpr (sizeof(TC) == 2) C[(size_t)m * N + n] = (TC)f2b(vv);
                else                            C[(size_t)m * N + n] = vv;
            }
        }
    }
}

// ---------------- MFMA flash attention (single-pass, proven) -----------------
__global__ __launch_bounds__(256) void attn_mfma_kernel(const unsigned short* __restrict__ q,
                                                        const unsigned short* __restrict__ k,
                                                        const unsigned short* __restrict__ v,
                                                        unsigned short* __restrict__ o) {
    constexpr int LDK = 72;
    constexpr int NT  = Sc / 64;
    __shared__ unsigned short Ks[2][64 * LDK];
    __shared__ unsigned short Vt[2][64 * LDK];

    int flat = blockIdx.x;
    int wg = (flat & 7) * 64 + (flat >> 3);
    int qt = wg & 31;
    int hb = wg >> 5;
    int hh = hb & 7, b = hb >> 3;

    int q0 = qt * 64;
    int tid = threadIdx.x;
    int wid = tid >> 6, lane = tid & 63;
    int lr = lane & 15, lg = lane >> 4;

    const unsigned short* kbase = k + (size_t)(b * Sc) * Hc + hh * 64;
    const unsigned short* vbase = v + (size_t)(b * Sc) * Hc + hh * 64;

    bf16x8 qf[2];
    {
        const unsigned short* qrow = q + ((size_t)(b * Sc + q0 + wid * 16 + lr)) * Hc + hh * 64;
        qf[0] = *(const bf16x8*)&qrow[8 * lg];
        qf[1] = *(const bf16x8*)&qrow[32 + 8 * lg];
    }

    int krow = tid >> 3;
    int kcol = (tid & 7) * 8;
    int vk2  = (tid >> 4) * 2;
    int vd4  = (tid & 15) * 4;

    bf16x8 kr[2];
    ushort4 va[2], vb2[2];

    auto load_tile = [&](int kt) {
        #pragma unroll
        for (int p = 0; p < 2; p++) {
            kr[p] = *(const bf16x8*)&kbase[(size_t)(kt * 64 + p * 32 + krow) * Hc + kcol];
            const unsigned short* vp = &vbase[(size_t)(kt * 64 + p * 32 + vk2) * Hc + vd4];
            va[p]  = *(const ushort4*)vp;
            vb2[p] = *(const ushort4*)(vp + Hc);
        }
    };
    auto vswz = [](int d, int c) { return c ^ (8 * ((d >> 3) & 7)); };
    auto store_tile = [&](int bu) {
        #pragma unroll
        for (int p = 0; p < 2; p++) {
            *(bf16x8*)&Ks[bu][(p * 32 + krow) * LDK + kcol] = kr[p];
            int k2 = p * 32 + vk2;
            *(ushort2*)&Vt[bu][(vd4 + 0) * LDK + vswz(vd4 + 0, k2)] = (ushort2){va[p].x, vb2[p].x};
            *(ushort2*)&Vt[bu][(vd4 + 1) * LDK + vswz(vd4 + 1, k2)] = (ushort2){va[p].y, vb2[p].y};
            *(ushort2*)&Vt[bu][(vd4 + 2) * LDK + vswz(vd4 + 2, k2)] = (ushort2){va[p].z, vb2[p].z};
            *(ushort2*)&Vt[bu][(vd4 + 3) * LDK + vswz(vd4 + 3, k2)] = (ushort2){va[p].w, vb2[p].w};
        }
    };

    f32x4 Oacc[4];
    #pragma unroll
    for (int nb = 0; nb < 4; nb++) Oacc[nb] = (f32x4){0.f, 0.f, 0.f, 0.f};
    float mrun = -1e30f, lrun = 0.f;
    const float SCL2 = 0.125f * 1.4426950408889634f;

    load_tile(0);
    store_tile(0);
    __syncthreads();

    for (int kt = 0; kt < NT; kt++) {
        int cur = kt & 1;
        if (kt + 1 < NT) load_tile(kt + 1);

        f32x4 sacc[4];
        #pragma unroll
        for (int kb = 0; kb < 4; kb++) sacc[kb] = (f32x4){0.f, 0.f, 0.f, 0.f};
        __builtin_amdgcn_s_setprio(1);
        #pragma unroll
        for (int kb = 0; kb < 4; kb++) {
            #pragma unroll
            for (int s = 0; s < 2; s++) {
                bf16x8 kf = *(const bf16x8*)&Ks[cur][(kb * 16 + lr) * LDK + 32 * s + 8 * lg];
                sacc[kb] = __builtin_amdgcn_mfma_f32_16x16x32_bf16(kf, qf[s], sacc[kb], 0, 0, 0);
            }
        }
        __builtin_amdgcn_s_setprio(0);

        float z[4][4];
        float mt = -1e30f;
        #pragma unroll
        for (int kb = 0; kb < 4; kb++)
            #pragma unroll
            for (int r = 0; r < 4; r++) {
                z[kb][r] = sacc[kb][r] * SCL2;
                mt = fmaxf(mt, z[kb][r]);
            }
        mt = fmaxf(mt, __shfl_xor(mt, 16));
        mt = fmaxf(mt, __shfl_xor(mt, 32));

        bool defer = __all(mt - mrun <= 11.0f);
        float pv[4][4];
        float ps = 0.f;
        if (defer) {
            #pragma unroll
            for (int kb = 0; kb < 4; kb++)
                #pragma unroll
                for (int r = 0; r < 4; r++) {
                    pv[kb][r] = __builtin_amdgcn_exp2f(z[kb][r] - mrun);
                    ps += pv[kb][r];
                }
            ps += __shfl_xor(ps, 16);
            ps += __shfl_xor(ps, 32);
            lrun += ps;
        } else {
            float mnew = fmaxf(mrun, mt);
            float sc = __builtin_amdgcn_exp2f(mrun - mnew);
            #pragma unroll
            for (int kb = 0; kb < 4; kb++)
                #pragma unroll
                for (int r = 0; r < 4; r++) {
                    pv[kb][r] = __builtin_amdgcn_exp2f(z[kb][r] - mnew);
                    ps += pv[kb][r];
                }
            ps += __shfl_xor(ps, 16);
            ps += __shfl_xor(ps, 32);
            lrun = lrun * sc + ps;
            mrun = mnew;
            float scb[4];
            #pragma unroll
            for (int r = 0; r < 4; r++) scb[r] = __shfl(sc, lg * 4 + r);
            #pragma unroll
            for (int nb = 0; nb < 4; nb++)
                #pragma unroll
                for (int r = 0; r < 4; r++) Oacc[nb][r] *= scb[r];
        }

        unsigned d_[4][2];
        #pragma unroll
        for (int kb = 0; kb < 4; kb++) {
            d_[kb][0] = cvt_pk_bf16(pv[kb][0], pv[kb][1]);
            d_[kb][1] = cvt_pk_bf16(pv[kb][2], pv[kb][3]);
        }
        unsigned pfw[2][4];
        #pragma unroll
        for (int s = 0; s < 2; s++) {
            #pragma unroll
            for (int h = 0; h < 2; h++) {
                unsigned xx = d_[2 * s][h], yy = d_[2 * s + 1][h];
                asm volatile("v_permlane32_swap_b32 %0, %1" : "+v"(xx), "+v"(yy));
                asm volatile("v_permlane16_swap_b32 %0, %1" : "+v"(xx), "+v"(yy));
                pfw[s][h]     = xx;
                pfw[s][2 + h] = yy;
            }
        }
        bf16x8 pf0, pf1;
        *(unsigned*)&((short*)&pf0)[0] = pfw[0][0];
        *(unsigned*)&((short*)&pf0)[2] = pfw[0][1];
        *(unsigned*)&((short*)&pf0)[4] = pfw[0][2];
        *(unsigned*)&((short*)&pf0)[6] = pfw[0][3];
        *(unsigned*)&((short*)&pf1)[0] = pfw[1][0];
        *(unsigned*)&((short*)&pf1)[2] = pfw[1][1];
        *(unsigned*)&((short*)&pf1)[4] = pfw[1][2];
        *(unsigned*)&((short*)&pf1)[6] = pfw[1][3];

        __builtin_amdgcn_s_setprio(1);
        #pragma unroll
        for (int nb = 0; nb < 4; nb++) {
            f32x4 oa = Oacc[nb];
            int vrow = nb * 16 + lr;
            bf16x8 vf0 = *(const bf16x8*)&Vt[cur][vrow * LDK + vswz(vrow, 8 * lg)];
            bf16x8 vf1 = *(const bf16x8*)&Vt[cur][vrow * LDK + vswz(vrow, 32 + 8 * lg)];
            oa = __builtin_amdgcn_mfma_f32_16x16x32_bf16(pf0, vf0, oa, 0, 0, 0);
            oa = __builtin_amdgcn_mfma_f32_16x16x32_bf16(pf1, vf1, oa, 0, 0, 0);
            Oacc[nb] = oa;
        }
        __builtin_amdgcn_s_setprio(0);

        if (kt + 1 < NT) store_tile(cur ^ 1);
        __syncthreads();
    }

    float linv = 1.0f / lrun;
    unsigned short* ob = o + ((size_t)(b * Sc + q0 + wid * 16)) * Hc + hh * 64;
    #pragma unroll
    for (int r = 0; r < 4; r++) {
        float invB = __shfl(linv, lg * 4 + r);
        #pragma unroll
        for (int nb = 0; nb < 4; nb++) {
            ob[(size_t)(lg * 4 + r) * Hc + nb * 16 + lr] = f2b(Oacc[nb][r] * invB);
        }
    }
}

// ---------------- fused LN2 + router + top-2 (exact fp32 gates) --------------
__global__ __launch_bounds__(256) void ln2_router_kernel(const float* __restrict__ xa,
                                                         const float* __restrict__ g,
                                                         const float* __restrict__ b,
                                                         const float* __restrict__ wr,
                                                         unsigned short* __restrict__ x2b,
                                                         int* __restrict__ ef,
                                                         float* __restrict__ gf) {
    int t = blockIdx.x;
    const float* row = xa + (size_t)t * Hc;
    int tid = threadIdx.x;
    int w = tid >> 6, l = tid & 63;
    float v0 = row[tid];
    float v1 = row[tid + 256];
    float s = v0 + v1, s2 = v0 * v0 + v1 * v1;
    for (int off = 32; off; off >>= 1) {
        s  += __shfl_down(s,  off);
        s2 += __shfl_down(s2, off);
    }
    __shared__ float ls[4], ls2[4];
    __shared__ float xn[512];
    __shared__ float part[4][64];
    if (l == 0) { ls[w] = s; ls2[w] = s2; }
    __syncthreads();
    if (tid == 0) {
        float a = 0.f, a2 = 0.f;
        for (int i = 0; i < 4; i++) { a += ls[i]; a2 += ls2[i]; }
        ls[0] = a; ls2[0] = a2;
    }
    __syncthreads();
    float mean = ls[0] * (1.0f / Hc);
    float var  = ls2[0] * (1.0f / Hc) - mean * mean;
    float r = rsqrtf(var + 1e-5f);
    float o0 = (v0 - mean) * r * g[tid]       + b[tid];
    float o1 = (v1 - mean) * r * g[tid + 256] + b[tid + 256];
    xn[tid] = o0; xn[tid + 256] = o1;
    x2b[(size_t)t * Hc + tid]       = f2b(o0);
    x2b[(size_t)t * Hc + tid + 256] = f2b(o1);
    __syncthreads();

    float acc = 0.f;
    const float* wrow = wr + (size_t)(w * 128) * Ec + l;
    #pragma unroll 8
    for (int hh = 0; hh < 128; hh++)
        acc += xn[w * 128 + hh] * wrow[(size_t)hh * Ec];
    part[w][l] = acc;
    __syncthreads();
    if (w == 0) {
        float logit = part[0][l] + part[1][l] + part[2][l] + part[3][l];
        float mx = logit;
        for (int off = 32; off; off >>= 1) mx = fmaxf(mx, __shfl_xor(mx, off));
        float p = __expf(logit - mx);
        float sum = p;
        for (int off = 32; off; off >>= 1) sum += __shfl_xor(sum, off);
        p /= sum;
        float v1_ = p; int i1 = l;
        for (int off = 32; off; off >>= 1) {
            float ov = __shfl_xor(v1_, off);
            int   oi = __shfl_xor(i1, off);
            if (ov > v1_ || (ov == v1_ && oi < i1)) { v1_ = ov; i1 = oi; }
        }
        float v2_ = (l == i1) ? -INFINITY : p; int i2 = l;
        for (int off = 32; off; off >>= 1) {
            float ov = __shfl_xor(v2_, off);
            int   oi = __shfl_xor(i2, off);
            if (ov > v2_ || (ov == v2_ && oi < i2)) { v2_ = ov; i2 = oi; }
        }
        if (l == 0) {
            float inv = 1.0f / (v1_ + v2_);
            ef[t * 2]     = i1;
            ef[t * 2 + 1] = i2;
            gf[t * 2]     = v1_ * inv;
            gf[t * 2 + 1] = v2_ * inv;
        }
    }
}

// ---------------- pos: rank of each slot within its expert (parallel scan) ---
__global__ __launch_bounds__(256) void pos_kernel(const int* __restrict__ ef,
                                                  int* __restrict__ pos) {
    int e = blockIdx.x;
    __shared__ int cnts[257];
    int tid = threadIdx.x;
    int base = tid * 32;  // 8192 / 256
    int c = 0;
    for (int i = 0; i < 32; i++) c += (ef[base + i] == e) ? 1 : 0;
    cnts[tid + 1] = c;
    if (tid == 0) cnts[0] = 0;
    __syncthreads();
    // Hillis-Steele inclusive scan over cnts[1..256]
    #pragma unroll
    for (int off = 1; off < 256; off <<= 1) {
        int v = cnts[tid + 1];
        int add = (tid + 1 > off) ? cnts[tid + 1 - off] : 0;
        __syncthreads();
        cnts[tid + 1] = v + add;
        __syncthreads();
    }
    int run = cnts[tid];
    for (int i = 0; i < 32; i++) {
        if (ef[base + i] == e) pos[base + i] = run++;
    }
}

// ---------------- dispatch: copy kept tokens (bf16 -> bf16) ------------------
__global__ __launch_bounds__(128) void dispatch_kernel(const unsigned short* __restrict__ x2b,
                                                       const int* __restrict__ ef,
                                                       const int* __restrict__ pos,
                                                       unsigned short* __restrict__ buf) {
    int s = blockIdx.x;
    int p = pos[s];
    if (p >= Cap) return;
    int e = ef[s];
    int t = s >> 1;
    ushort4 vv = ((const ushort4*)(x2b + (size_t)t * Hc))[threadIdx.x];
    ((ushort4*)(buf + ((size_t)e * Cap + p) * Hc))[threadIdx.x] = vv;
}

// ---------------- combine: out = xa + sum_k gate * y[ef,pos] (y bf16) --------
__global__ __launch_bounds__(128) void combine_kernel(const float* __restrict__ xa,
                                                      const unsigned short* __restrict__ y,
                                                      const int* __restrict__ ef,
                                                      const int* __restrict__ pos,
                                                      const float* __restrict__ gf,
                                                      float* __restrict__ out) {
    int t = blockIdx.x;
    int d = threadIdx.x;
    float4 acc = ((const float4*)(xa + (size_t)t * Hc))[d];
    #pragma unroll
    for (int kk = 0; kk < 2; kk++) {
        int s = t * 2 + kk;
        int p = pos[s];
        if (p < Cap) {
            float w = gf[s];
            ushort4 yv = ((const ushort4*)(y + ((size_t)ef[s] * Cap + p) * Hc))[d];
            acc.x += w * b2f(yv.x);
            acc.y += w * b2f(yv.y);
            acc.z += w * b2f(yv.z);
            acc.w += w * b2f(yv.w);
        }
    }
    ((float4*)(out + (size_t)t * Hc))[d] = acc;
}

// ---------------- launch -----------------------------------------------------
extern "C" void kernel_launch(void* const* d_in, const int* in_sizes, int n_in,
                              void* d_out, int out_size, void* d_ws, size_t ws_size,
                              hipStream_t stream) {
    const float* x     = (const float*)d_in[0];
    const float* ln1_g = (const float*)d_in[1];
    const float* ln1_b = (const float*)d_in[2];
    const float* wq    = (const float*)d_in[3];
    const float* wk    = (const float*)d_in[4];
    const float* wv    = (const float*)d_in[5];
    const float* wo    = (const float*)d_in[6];
    const float* ln2_g = (const float*)d_in[7];
    const float* ln2_b = (const float*)d_in[8];
    const float* wr    = (const float*)d_in[9];
    const float* w1    = (const float*)d_in[10];
    const float* b1    = (const float*)d_in[11];
    const float* w2    = (const float*)d_in[12];
    const float* b2    = (const float*)d_in[13];
    float* out = (float*)d_out;

    const size_t TH   = (size_t)Tc * Hc;        // 2,097,152
    const size_t ECH  = (size_t)Ec * Cap * Hc;  // 8,388,608
    const size_t ECF  = (size_t)Ec * Cap * Fc;  // 33,554,432
    const size_t HF   = (size_t)Hc * Fc;        // 1,048,576 (per-expert w size)

    // ---- workspace carve (bytes) ----
    char* wsb = (char*)d_ws;
    size_t off = 0;
    auto alloc = [&](size_t bytes) { size_t r = off; off = (off + bytes + 255) & ~(size_t)255; return r; };
    size_t x1b_off = alloc(TH * 2);       // bf16 x1
    size_t qkv_off = alloc(TH * 2 * 3);   // bf16 q|k|v contiguous
    size_t ab_off  = alloc(TH * 2);       // bf16 attention output
    size_t xa_off  = alloc(TH * 4);       // fp32 attn residual out
    size_t x2b_off = alloc(TH * 2);       // bf16 LN2 out
    size_t ef_off  = alloc((size_t)Tc * 2 * 4);
    size_t pos_off = alloc((size_t)Tc * 2 * 4);
    size_t gf_off  = alloc((size_t)Tc * 2 * 4);
    size_t buf_off = alloc(ECH * 2);      // bf16 expert inputs
    size_t h_off   = alloc(ECF * 2);      // bf16 h (all experts)
    size_t y_off   = alloc(ECH * 2);      // bf16 expert outputs
    if (ws_size < off) return;            // insufficient workspace

    unsigned short* x1b  = (unsigned short*)(wsb + x1b_off);
    unsigned short* qb   = (unsigned short*)(wsb + qkv_off);
    unsigned short* kb   = qb + TH;
    unsigned short* vb   = qb + 2 * TH;
    unsigned short* ab   = (unsigned short*)(wsb + ab_off);
    float* xa  = (float*)(wsb + xa_off);
    unsigned short* x2b = (unsigned short*)(wsb + x2b_off);
    int*   ef  = (int*)(wsb + ef_off);
    int*   pos = (int*)(wsb + pos_off);
    float* gf  = (float*)(wsb + gf_off);
    unsigned short* bufb = (unsigned short*)(wsb + buf_off);
    unsigned short* h    = (unsigned short*)(wsb + h_off);
    unsigned short* y    = (unsigned short*)(wsb + y_off);

    dim3 blk(256);

    // 1. LN1 -> bf16 (wave per row)
    ln_rows_kernel<<<Tc / 4, blk, 0, stream>>>(x, ln1_g, ln1_b, x1b);

    // 2. fused QKV projections: one launch, z selects {wq,wk,wv} -> q|k|v
    gemm_mfma<128, 0, 0, unsigned short><<<dim3(Hc / 128, Tc / 128, 3), blk, 0, stream>>>(
        x1b, wq, qb, nullptr, Tc, Hc, Hc, 0, 0, (long)TH, 0, wk, wv);

    // 3. attention -> bf16 ab (single-pass, XCD-swizzled)
    attn_mfma_kernel<<<dim3(512), blk, 0, stream>>>(qb, kb, vb, ab);

    // 4. output projection + residual: xa = attn @ wo + x
    gemm_mfma<128, 1, 0, float><<<dim3(Hc / 128, Tc / 128, 1), blk, 0, stream>>>(
        ab, wo, xa, x, Tc, Hc, Hc, 0, 0, 0, 0, nullptr, nullptr);

    // 5. fused LN2 + router + top2 -> x2b, ef, gf
    ln2_router_kernel<<<Tc, blk, 0, stream>>>(xa, ln2_g, ln2_b, wr, x2b, ef, gf);

    // 6. positions within expert queues
    pos_kernel<<<Ec, blk, 0, stream>>>(ef, pos);

    // 7. dispatch tokens to expert buffers (bf16 copy)
    dispatch_kernel<<<Tc * 2, dim3(128), 0, stream>>>(x2b, ef, pos, bufb);

    // 8. expert GEMM1: h = gelu(buf @ w1 + b1), BM=256 (w1 read exactly once)
    gemm_mfma<256, 2, 1, unsigned short><<<dim3(Fc / 128, Cap / 256, Ec), dim3(512), 0, stream>>>(
        bufb, w1, h, b1, Cap, Fc, Hc,
        (long)Cap * Hc, (long)HF, (long)Cap * Fc, (long)Fc, nullptr, nullptr);

    // 9. expert GEMM2: y = h @ w2 + b2 (bf16 out, XCD-swizzled)
    gemm_mfma<256, 3, 1, unsigned short><<<dim3(Hc / 128, Cap / 256, Ec), dim3(512), 0, stream>>>(
        h, w2, y, b2, Cap, Hc, Fc,
        (long)Cap * Fc, (long)HF, (long)Cap * Hc, (long)Hc, nullptr, nullptr);

    // 10. combine + final residual
    combine_kernel<<<Tc, dim3(128), 0, stream>>>(xa, y, ef, pos, gf, out);
}